// Round 7
// baseline (842.978 us; speedup 1.0000x reference)
//
#include <hip/hip_runtime.h>
#include <cmath>

// CfC-NCP RNN, phase-decomposed + chunk-pipelined.
// R12: R11 (persistent non-cooperative kernel) with the init bug fixed.
// R11 ROOT CAUSE: NCNT=512 counter ints, but pack zeroed them with
// `threadIdx.x < NCNT` in a 256-thread block -> X1DONE (idx 256-368) and
// R12DONE (idx 384-496) were NEVER initialized. First run over garbage ws:
// r12 saw X1DONE>=64 instantly and consumed uninitialized XU1 -> absmax 0.52.
// Fix: hipMemsetAsync(CNT) before pack (graph-capture legal) + grid-stride
// zeroing loop in pack. Protocol unchanged (R10-proven release/acquire):
//   X0DONE[c] (128): XU0[c&1] ready        -> r0(c) starts
//   R0DONE[c] (16):  NH0[c&1] ready        -> x1(c) starts; XU0[c&1] free
//   X1DONE[c] (64):  XU1[c&1] ready        -> r12(c) starts; NH0[c&1] free
//   R12DONE[c] (16):                          XU1[c&1] free
// Acyclic; steady-state waits pre-satisfied -> r0 runs 512 steps boundary-free.
// h0/h12 LDS-resident. 224 WGs co-resident (R9 verified). 2 launches total.
// Carried: packed weights, merged -(ts*wa+wb), -2*log2e pre-scale, depth-4 r0
// xu prefetch, depth-2 r12 xu prefetch, raw lgkmcnt-only barriers, single-rcp
// exp2 epilogue. R8/R6 lesson: r12 stays recurrent-only with bulk x1.

typedef _Float16 f16;
typedef f16 h4 __attribute__((ext_vector_type(4)));
typedef f16 h8 __attribute__((ext_vector_type(8)));
typedef float f4 __attribute__((ext_vector_type(4)));

#define MFMA(a, b, c) __builtin_amdgcn_mfma_f32_16x16x32_f16(a, b, c, 0, 0, 0)
#define RAW_BAR() asm volatile("s_waitcnt lgkmcnt(0)\n\ts_barrier" ::: "memory")

constexpr int IN_DIM = 128, Ni = 149, Nc = 99, Nm = 8;
constexpr int CAT0 = 277, CAT1 = 248, CAT2 = 107;
constexpr int Bsz = 256, Tsz = 512;
constexpr int TC = 64, NCH = 8, NBT = 16;
constexpr int NT0 = 30, NT1 = 21;        // fragment tile-columns (3 mats x n-tiles)
constexpr int S0 = 168, S2 = 136;        // LDS row strides (halves), bank-conflict pad
constexpr int NXWG1 = 64;                // x1 workgroups
constexpr int NXWG0 = 128;               // x0 workgroups
constexpr size_t XU0C = (size_t)TC * NBT * NT0 * 256;  // 7,864,320 halves / buffer
constexpr size_t NH0C = (size_t)TC * NBT * 2560;       // 2,621,440 halves / buffer
constexpr size_t XU1C = (size_t)TC * NBT * NT1 * 256;  // 5,505,024 halves / buffer
constexpr size_t YOFF = (size_t)Bsz * Tsz * 8;  // h_out offset in d_out
constexpr float L2E = 1.4426950408889634f;      // log2(e), folded into weights

// packed-fragment segment offsets (h8 units); mat2 = merged -(ts*wa+wb)
constexpr int OFF_X0 = 0;          // [mat3][nt10][kt4][lane64]
constexpr int OFF_R0 = 7680;       // [g10][mat3][kt5][lane64]
constexpr int OFF_X1 = 17280;      // [mat3][nt7][kt5][lane64]
constexpr int OFF_R12A = 24000;    // [w7][mat3][kt4][lane64]
constexpr int OFF_R12B = 29376;    // [mat3][kt4][lane64]
constexpr int NFRAG = 30144;

// handshake counters: 4 families x 8 chunks, padded to 64B apart
constexpr int CSTRIDE = 16;        // ints between counters (64B)
constexpr int C_X0 = 0, C_R0 = 8, C_X1 = 16, C_R12 = 24;
constexpr int NCNT = 32 * CSTRIDE; // 512 ints (2 KiB)

__device__ inline float rcpf_(float x) { return __builtin_amdgcn_rcpf(x); }
__device__ __forceinline__ float exp2p_(float x) {
#if __has_builtin(__builtin_amdgcn_exp2f)
  return __builtin_amdgcn_exp2f(x);
#else
  return exp2f(x);
#endif
}
// h = ff1 + (ff2-ff1)*ti with ff=(1-e)/(1+e), ti=1/(1+c).
// a0=-2u1*L2E, a1=-2u2*L2E, a2=-z*L2E (scales pre-folded into weights/biases).
__device__ __forceinline__ float cfc_h(float a0, float a1, float a2) {
  float e0 = exp2p_(a0), e1 = exp2p_(a1), e2 = exp2p_(a2);
  float pa = 1.f + e0, ma = 1.f - e0;
  float pb = 1.f + e1, mb = 1.f - e1;
  float pc = 1.f + e2;
  float num = fmaf(ma * pb, e2, mb * pa);
  return num * rcpf_(pa * pb * pc);
}
__device__ __forceinline__ float tanhp_(float x) {  // tanh(x)
  float e = exp2p_(-2.f * L2E * x);
  return (1.f - e) * rcpf_(1.f + e);
}

// ---- handshake primitives (R10-proven agent-scope release/acquire) ------------------
__device__ __forceinline__ void spin_ge(int* p, int target) {
  if (threadIdx.x == 0) {
    if (__hip_atomic_load(p, __ATOMIC_RELAXED, __HIP_MEMORY_SCOPE_AGENT) < target) {
      long it = 0;
      do {
        __builtin_amdgcn_s_sleep(4);
      } while (__hip_atomic_load(p, __ATOMIC_RELAXED, __HIP_MEMORY_SCOPE_AGENT) <
                   target &&
               ++it < (1L << 22));
    }
  }
  __syncthreads();
  __builtin_amdgcn_fence(__ATOMIC_ACQUIRE, "agent");
}
// __syncthreads drains vmcnt for ALL waves' stores; tid0's release-add then
// publishes (L2 writeback) before incrementing.
__device__ __forceinline__ void signal(int* p) {
  __syncthreads();
  if (threadIdx.x == 0)
    __hip_atomic_fetch_add(p, 1, __ATOMIC_RELEASE, __HIP_MEMORY_SCOPE_AGENT);
}

// ---------------- pack: build all h8 weight fragments + zero counters ----------------
__global__ __launch_bounds__(256) void pack_kernel(
    const float* __restrict__ w1_0, const float* __restrict__ w2_0,
    const float* __restrict__ wa_0, const float* __restrict__ wb_0,
    const int* __restrict__ m0,
    const float* __restrict__ w1_1, const float* __restrict__ w2_1,
    const float* __restrict__ wa_1, const float* __restrict__ wb_1,
    const int* __restrict__ m1,
    const float* __restrict__ w1_2, const float* __restrict__ w2_2,
    const float* __restrict__ wa_2, const float* __restrict__ wb_2,
    const int* __restrict__ m2, const float* __restrict__ dtp,
    f16* __restrict__ PK, int* __restrict__ CNT) {
  // R12 FIX: grid-stride zeroing covers ALL NCNT=512 ints (R11 only hit 0-255).
  if (blockIdx.x == 0)
    for (int i = threadIdx.x; i < NCNT; i += 256)
      __hip_atomic_store(&CNT[i], 0, __ATOMIC_RELAXED, __HIP_MEMORY_SCOPE_AGENT);
  int idx = blockIdx.x * 256 + threadIdx.x;
  if (idx >= NFRAG) return;
  int lane = idx & 63, col = lane & 15, q = lane >> 4;
  float ts = dtp[0];
  const float* Wa = nullptr;
  const float* Wb = nullptr;
  const int* M = nullptr;
  int ld, n, nmax, k0, kmax;
  int mat;
  if (idx < OFF_R0) {  // x0 input-part
    int p = idx >> 6;
    mat = p / 40; int nt = (p >> 2) % 10, kt = p & 3;
    ld = CAT0; n = nt * 16 + col; nmax = Ni; k0 = kt * 32 + q * 8; kmax = IN_DIM;
    if (mat == 0) { Wa = w1_0; M = m0; }
    else if (mat == 1) { Wa = w2_0; M = m0; }
    else { Wa = wa_0; Wb = wb_0; }
  } else if (idx < OFF_X1) {  // r0 recurrent-part
    int p = (idx - OFF_R0) >> 6;
    int g = p / 15; mat = (p / 5) % 3; int kt = p % 5;
    ld = CAT0; n = g * 16 + col; nmax = Ni; k0 = IN_DIM + kt * 32 + q * 8; kmax = CAT0;
    if (mat == 0) Wa = w1_0;
    else if (mat == 1) Wa = w2_0;
    else { Wa = wa_0; Wb = wb_0; }
  } else if (idx < OFF_R12A) {  // x1 input-part
    int p = (idx - OFF_X1) >> 6;
    mat = p / 35; int nt = (p / 5) % 7, kt = p % 5;
    ld = CAT1; n = nt * 16 + col; nmax = Nc; k0 = kt * 32 + q * 8; kmax = Ni;
    if (mat == 0) { Wa = w1_1; M = m1; }
    else if (mat == 1) { Wa = w2_1; M = m1; }
    else { Wa = wa_1; Wb = wb_1; }
  } else if (idx < OFF_R12B) {  // r12 layer1 recurrent-part
    int p = (idx - OFF_R12A) >> 6;
    int wv = p / 12; mat = (p / 4) % 3; int kt = p & 3;
    ld = CAT1; n = wv * 16 + col; nmax = Nc; k0 = Ni + kt * 32 + q * 8; kmax = CAT1;
    if (mat == 0) Wa = w1_1;
    else if (mat == 1) Wa = w2_1;
    else { Wa = wa_1; Wb = wb_1; }
  } else {  // r12 layer2 (full cat)
    int p = (idx - OFF_R12B) >> 6;
    mat = p / 4; int kt = p & 3;
    ld = CAT2; n = col; nmax = Nm; k0 = kt * 32 + q * 8; kmax = CAT2;
    if (mat == 0) { Wa = w1_2; M = m2; }
    else if (mat == 1) { Wa = w2_2; M = m2; }
    else { Wa = wa_2; Wb = wb_2; }
  }
  h8 r;
#pragma unroll
  for (int j = 0; j < 8; j++) {
    int k = k0 + j;
    float v = 0.f;
    if (n < nmax && k < kmax) {
      if (mat < 2) {
        v = Wa[(size_t)n * ld + k];
        if (M) v *= (float)M[(size_t)n * ld + k];
        v *= -2.f * L2E;                 // ff pre-scale: acc = -2u*log2(e)
      } else {
        v = -L2E * (ts * Wa[(size_t)n * ld + k] + Wb[(size_t)n * ld + k]);
      }
    }
    r[j] = (f16)v;
  }
  ((h8*)PK)[idx] = r;
}

// ------- r0 one step: consume xu (t), reload xu for t+4 (depth-4 pipeline) -----------
__device__ __forceinline__ void r0_step(
    const f16* br, f16* bw, const f16* __restrict__ XU0, f16* __restrict__ NH0,
    float* __restrict__ out, const h8 (&Bf)[3][5], h4 (&xu)[3],
    int t, int tload, int bt, int g, int lane, int col, int q, int n, bool last) {
  h8 A[5];
#pragma unroll
  for (int kt = 0; kt < 5; kt++)
    A[kt] = *(const h8*)(br + col * S0 + kt * 32 + q * 8);
  f4 acc0 = {(float)xu[0][0], (float)xu[0][1], (float)xu[0][2], (float)xu[0][3]};
  f4 acc1 = {(float)xu[1][0], (float)xu[1][1], (float)xu[1][2], (float)xu[1][3]};
  f4 acc2 = {(float)xu[2][0], (float)xu[2][1], (float)xu[2][2], (float)xu[2][3]};
  size_t mtl = (size_t)tload * NBT + bt;
#pragma unroll
  for (int mat = 0; mat < 3; mat++)
    xu[mat] = *(const h4*)(XU0 + (mtl * NT0 + mat * 10 + g) * 256 + lane * 4);
#pragma unroll
  for (int kt = 0; kt < 5; kt++) {
    acc0 = MFMA(A[kt], Bf[0][kt], acc0);
    acc1 = MFMA(A[kt], Bf[1][kt], acc1);
    acc2 = MFMA(A[kt], Bf[2][kt], acc2);
  }
  int mt = t * NBT + bt;
  f16* nh = NH0 + (size_t)mt * 2560;
#pragma unroll
  for (int r = 0; r < 4; r++) {
    int m = q * 4 + r;
    float h = cfc_h(acc0[r], acc1[r], acc2[r]);
    f16 h16 = (f16)h;
    bw[m * S0 + n] = h16;
    nh[m * 160 + n] = h16;   // cols >= Ni are exact zeros (zero weights+bias)
    if (last && n < Ni) out[YOFF + (size_t)(bt * 16 + m) * 256 + n] = h;
  }
}

// ------- r12 layer1 one step: consume xu(t), reload xu for t+2 -----------------------
__device__ __forceinline__ void r12l1_step(
    const f16* br, f16* bw, const f16* __restrict__ XU1, float* __restrict__ out,
    const h8 (&Bf)[3][4], h4 (&xu)[3],
    int tload, int bt, int w, int lane, int col, int q, int n, bool last) {
  h8 A[4];
#pragma unroll
  for (int kt = 0; kt < 4; kt++)
    A[kt] = *(const h8*)(br + col * S2 + kt * 32 + q * 8);
  f4 acc0 = {(float)xu[0][0], (float)xu[0][1], (float)xu[0][2], (float)xu[0][3]};
  f4 acc1 = {(float)xu[1][0], (float)xu[1][1], (float)xu[1][2], (float)xu[1][3]};
  f4 acc2 = {(float)xu[2][0], (float)xu[2][1], (float)xu[2][2], (float)xu[2][3]};
  size_t mtl = (size_t)tload * NBT + bt;
#pragma unroll
  for (int mat = 0; mat < 3; mat++)
    xu[mat] = *(const h4*)(XU1 + (mtl * NT1 + mat * 7 + w) * 256 + lane * 4);
#pragma unroll
  for (int kt = 0; kt < 4; kt++) {
    acc0 = MFMA(A[kt], Bf[0][kt], acc0);
    acc1 = MFMA(A[kt], Bf[1][kt], acc1);
    acc2 = MFMA(A[kt], Bf[2][kt], acc2);
  }
#pragma unroll
  for (int r = 0; r < 4; r++) {
    int m = q * 4 + r;
    float h = cfc_h(acc0[r], acc1[r], acc2[r]);
    if (n < Nc) {
      bw[m * S2 + n] = (f16)h;
      if (last) out[YOFF + (size_t)(bt * 16 + m) * 256 + Ni + n] = h;
    }
  }
}

// ------- r12 layer2 one step: reads rb (nh1(t)|h2(t-1)), writes h2(t) into wb --------
__device__ __forceinline__ void r12l2_step(
    const f16* rb, f16* wb, float* __restrict__ out, const h8 (&Bf)[3][4],
    float bn0, float bn1, float bn2, int tg, int bt, int col, int q, bool last) {
  h8 A[4];
#pragma unroll
  for (int kt = 0; kt < 4; kt++)
    A[kt] = *(const h8*)(rb + col * S2 + kt * 32 + q * 8);
  f4 acc0 = {bn0, bn0, bn0, bn0};
  f4 acc1 = {bn1, bn1, bn1, bn1};
  f4 acc2 = {bn2, bn2, bn2, bn2};
#pragma unroll
  for (int kt = 0; kt < 4; kt++) {
    acc0 = MFMA(A[kt], Bf[0][kt], acc0);
    acc1 = MFMA(A[kt], Bf[1][kt], acc1);
    acc2 = MFMA(A[kt], Bf[2][kt], acc2);
  }
#pragma unroll
  for (int r = 0; r < 4; r++) {
    int m = q * 4 + r;
    float h = cfc_h(acc0[r], acc1[r], acc2[r]);
    if (col < Nm) {
      out[((size_t)(bt * 16 + m) * Tsz + tg) * 8 + col] = tanhp_(h);
      wb[m * S2 + Nc + col] = (f16)h;
      if (last) out[YOFF + (size_t)(bt * 16 + m) * 256 + Ni + Nc + col] = h;
    }
  }
}

// ---- persistent R: [r0 0-15 | r12 16-31 | x1 32-95 | x0 96-223], handshake-driven ---
__global__ __launch_bounds__(640) void R_kernel(
    const h8* __restrict__ pk,
    const float* __restrict__ b1_0, const float* __restrict__ b2_0,
    const float* __restrict__ ba_0, const float* __restrict__ bb_0,
    const float* __restrict__ b1_1, const float* __restrict__ b2_1,
    const float* __restrict__ ba_1, const float* __restrict__ bb_1,
    const float* __restrict__ c1, const float* __restrict__ c2,
    const float* __restrict__ ca, const float* __restrict__ cb,
    const float* __restrict__ dtp, const float* __restrict__ x,
    f16* __restrict__ XU0, f16* __restrict__ NH0, f16* __restrict__ XU1,
    int* __restrict__ CNT, float* __restrict__ out) {
  __shared__ __align__(16) char smem[10752];  // union: r0 10752 / r12 8704 / x0 4352
  int tid = threadIdx.x;
  int g = tid >> 6, lane = tid & 63, col = lane & 15, q = lane >> 4;
  int wg = blockIdx.x;
  float ts = dtp[0];

  if (wg < NBT) {  // ================= r0: chunks 0..NCH-1, no boundaries =============
    f16(*buf)[16 * S0] = (f16(*)[16 * S0])smem;
    int bt = wg;
    int n = g * 16 + col;                      // output neuron (0..159, valid <149)
    h8 Bf[3][5];                               // recurrent weights, resident all run
#pragma unroll
    for (int mat = 0; mat < 3; mat++)
#pragma unroll
      for (int kt = 0; kt < 5; kt++)
        Bf[mat][kt] = pk[OFF_R0 + ((g * 3 + mat) * 5 + kt) * 64 + lane];
    for (int idx = tid; idx < 2 * 16 * S0; idx += 640) ((f16*)buf)[idx] = (f16)0.f;
    __syncthreads();

    for (int c = 0; c < NCH; ++c) {
      spin_ge(&CNT[(C_X0 + c) * CSTRIDE], NXWG0);          // XU0[c&1] ready
      if (c >= 2) spin_ge(&CNT[(C_X1 + c - 2) * CSTRIDE], NXWG1);  // NH0[c&1] free
      const f16* XU0r = XU0 + (size_t)(c & 1) * XU0C;
      f16* NH0w = NH0 + (size_t)(c & 1) * NH0C;
      h4 xu0[3], xu1[3], xu2[3], xu3[3];       // depth-4 prefetch (2-step lead)
#pragma unroll
      for (int mat = 0; mat < 3; mat++) {
        xu0[mat] = *(const h4*)(XU0r + ((size_t)(0 * NBT + bt) * NT0 + mat * 10 + g) * 256 + lane * 4);
        xu1[mat] = *(const h4*)(XU0r + ((size_t)(1 * NBT + bt) * NT0 + mat * 10 + g) * 256 + lane * 4);
        xu2[mat] = *(const h4*)(XU0r + ((size_t)(2 * NBT + bt) * NT0 + mat * 10 + g) * 256 + lane * 4);
        xu3[mat] = *(const h4*)(XU0r + ((size_t)(3 * NBT + bt) * NT0 + mat * 10 + g) * 256 + lane * 4);
      }
      for (int t = 0; t < TC; t += 4) {
        r0_step(buf[0], buf[1], XU0r, NH0w, out, Bf, xu0, t, (t + 4 < TC) ? t + 4 : t,
                bt, g, lane, col, q, n, false);
        RAW_BAR();
        r0_step(buf[1], buf[0], XU0r, NH0w, out, Bf, xu1, t + 1,
                (t + 5 < TC) ? t + 5 : t + 1, bt, g, lane, col, q, n, false);
        RAW_BAR();
        r0_step(buf[0], buf[1], XU0r, NH0w, out, Bf, xu2, t + 2,
                (t + 6 < TC) ? t + 6 : t + 2, bt, g, lane, col, q, n, false);
        RAW_BAR();
        bool lastD = (c == NCH - 1) && (t + 3 == TC - 1);
        r0_step(buf[1], buf[0], XU0r, NH0w, out, Bf, xu3, t + 3,
                (t + 7 < TC) ? t + 7 : t + 3, bt, g, lane, col, q, n, lastD);
        RAW_BAR();
      }
      signal(&CNT[(C_R0 + c) * CSTRIDE]);      // NH0[c&1] published (syncthreads
                                               // drains vmcnt; release does wb)
    }

  } else if (wg < 2 * NBT) {  // ================= r12: chunks 0..NCH-1 ================
    f16(*buf)[16 * S2] = (f16(*)[16 * S2])smem;
    int bt = wg - NBT;
    int w = g;                                 // wave id 0..9 (8,9 barrier-only)
    int n = w * 16 + col;
    h8 Bf[3][4];
    float bn0 = 0.f, bn1 = 0.f, bn2 = 0.f;
    if (w < 7) {
#pragma unroll
      for (int mat = 0; mat < 3; mat++)
#pragma unroll
        for (int kt = 0; kt < 4; kt++)
          Bf[mat][kt] = pk[OFF_R12A + ((w * 3 + mat) * 4 + kt) * 64 + lane];
    } else if (w == 7) {
#pragma unroll
      for (int mat = 0; mat < 3; mat++)
#pragma unroll
        for (int kt = 0; kt < 4; kt++)
          Bf[mat][kt] = pk[OFF_R12B + (mat * 4 + kt) * 64 + lane];
      bn0 = (col < Nm) ? -2.f * L2E * c1[col] : 0.f;
      bn1 = (col < Nm) ? -2.f * L2E * c2[col] : 0.f;
      bn2 = (col < Nm) ? -L2E * (ts * ca[col] + cb[col]) : 0.f;
    }
    for (int idx = tid; idx < 2 * 16 * S2; idx += 640) ((f16*)buf)[idx] = (f16)0.f;
    __syncthreads();

    for (int cc = 0; cc < NCH; ++cc) {
      spin_ge(&CNT[(C_X1 + cc) * CSTRIDE], NXWG1);         // XU1[cc&1] ready
      const f16* XU1r = XU1 + (size_t)(cc & 1) * XU1C;
      h4 xuA[3], xuB[3];                       // depth-2 prefetch register sets
      if (w < 7) {
#pragma unroll
        for (int mat = 0; mat < 3; mat++) {
          xuA[mat] = *(const h4*)(XU1r + ((size_t)bt * NT1 + mat * 7 + w) * 256 + lane * 4);
          xuB[mat] = *(const h4*)(XU1r +
                                  ((size_t)(NBT + bt) * NT1 + mat * 7 + w) * 256 + lane * 4);
        }
      }
      for (int t = 0; t < TC; t += 2) {
        if (w < 7) {
          int tlA = (t + 2 < TC) ? t + 2 : t;
          r12l1_step(buf[0], buf[1], XU1r, out, Bf, xuA, tlA, bt, w, lane, col, q, n,
                     false);                                // last never hits even t
        }
        RAW_BAR();
        if (w == 7)
          r12l2_step(buf[1], buf[0], out, Bf, bn0, bn1, bn2, cc * TC + t, bt, col, q,
                     false);
        if (w < 7) {
          int tlB = (t + 3 < TC) ? t + 3 : t + 1;
          bool lastB = (cc == NCH - 1) && (t + 1 == TC - 1);
          r12l1_step(buf[1], buf[0], XU1r, out, Bf, xuB, tlB, bt, w, lane, col, q, n,
                     lastB);
        }
        RAW_BAR();
        if (w == 7)
          r12l2_step(buf[0], buf[1], out, Bf, bn0, bn1, bn2, cc * TC + t + 1, bt, col,
                     q, (cc == NCH - 1) && (t + 1 == TC - 1));
      }
      signal(&CNT[(C_R12 + cc) * CSTRIDE]);    // XU1[cc&1] free for x1(cc+2)
    }

  } else if (wg < 2 * NBT + NXWG1) {  // ================= x1: chunks 0..NCH-1 =========
    int bx = wg - 2 * NBT;                     // 0..NXWG1-1
    int w = g;                                 // waves 0-6 active, 7-9 spin/sync only
    int n = w * 16 + col;
    h8 Bf[3][5];
    float bias[3] = {0.f, 0.f, 0.f};
    if (w < 7) {
#pragma unroll
      for (int mat = 0; mat < 3; mat++)
#pragma unroll
        for (int kt = 0; kt < 5; kt++)
          Bf[mat][kt] = pk[OFF_X1 + (mat * 35 + w * 5 + kt) * 64 + lane];
      bias[0] = (n < Nc) ? -2.f * L2E * b1_1[n] : 0.f;
      bias[1] = (n < Nc) ? -2.f * L2E * b2_1[n] : 0.f;
      bias[2] = (n < Nc) ? -L2E * (ts * ba_1[n] + bb_1[n]) : 0.f;
    }
    for (int cx = 0; cx < NCH; ++cx) {
      spin_ge(&CNT[(C_R0 + cx) * CSTRIDE], NBT);           // NH0[cx&1] ready
      if (cx >= 2) spin_ge(&CNT[(C_R12 + cx - 2) * CSTRIDE], NBT);  // XU1 free
      const f16* NH0r = NH0 + (size_t)(cx & 1) * NH0C;
      f16* XU1w = XU1 + (size_t)(cx & 1) * XU1C;
      if (w < 7) {
        for (int i = 0; i < (TC * NBT) / NXWG1; i++) {     // 16 mt tiles per WG
          int mt = bx * ((TC * NBT) / NXWG1) + i;
          const f16* Ab = NH0r + (size_t)mt * 2560;        // 16x160 halves, zero-pad
          h8 A[5];
#pragma unroll
          for (int kt = 0; kt < 5; kt++)
            A[kt] = *(const h8*)(Ab + col * 160 + kt * 32 + q * 8);
#pragma unroll
          for (int mat = 0; mat < 3; mat++) {
            float b = bias[mat];
            f4 acc = {b, b, b, b};
#pragma unroll
            for (int kt = 0; kt < 5; kt++) acc = MFMA(A[kt], Bf[mat][kt], acc);
            h4 o;
#pragma unroll
            for (int rr = 0; rr < 4; rr++) o[rr] = (f16)acc[rr];
            *(h4*)(XU1w + ((size_t)mt * NT1 + mat * 7 + w) * 256 + lane * 4) = o;
          }
        }
      }
      signal(&CNT[(C_X1 + cx) * CSTRIDE]);
    }

  } else {  // ================= x0: chunks 0..NCH-1 ==================================
    f16* stg = (f16*)smem;                     // 16 x 136
    int bx = wg - 2 * NBT - NXWG1;             // 0..NXWG0-1
    int w = g;                                 // wave -> output tile g=w, all 3 mats
    int n = w * 16 + col;
    h8 Bx[3][4];
    float bias[3];
#pragma unroll
    for (int mat = 0; mat < 3; mat++)
#pragma unroll
      for (int kt = 0; kt < 4; kt++)
        Bx[mat][kt] = pk[OFF_X0 + ((mat * 10 + w) * 4 + kt) * 64 + lane];
    bias[0] = (n < Ni) ? -2.f * L2E * b1_0[n] : 0.f;
    bias[1] = (n < Ni) ? -2.f * L2E * b2_0[n] : 0.f;
    bias[2] = (n < Ni) ? -L2E * (ts * ba_0[n] + bb_0[n]) : 0.f;
    for (int cn = 0; cn < NCH; ++cn) {
      if (cn >= 2) spin_ge(&CNT[(C_R0 + cn - 2) * CSTRIDE], NBT);   // XU0 free
      f16* XU0w = XU0 + (size_t)(cn & 1) * XU0C;
      for (int i = 0; i < (TC * NBT) / NXWG0; i++) {       // 8 mt tiles per WG
        int mt = bx * ((TC * NBT) / NXWG0) + i;
        int tl = mt >> 4, bt = mt & 15;
        int tg = cn * TC + tl;
        if (tid < 256) {
          int sr = tid >> 4, sc = (tid & 15) * 8;
          const float* xp = x + ((size_t)(bt * 16 + sr) * Tsz + tg) * IN_DIM + sc;
          h8 hv;
#pragma unroll
          for (int j = 0; j < 8; j++) hv[j] = (f16)xp[j];
          *(h8*)(stg + sr * 136 + sc) = hv;
        }
        __syncthreads();
        h8 A[4];
#pragma unroll
        for (int kt = 0; kt < 4; kt++)
          A[kt] = *(const h8*)(stg + col * 136 + kt * 32 + q * 8);
#pragma unroll
        for (int mat = 0; mat < 3; mat++) {
          float b = bias[mat];
          f4 acc = {b, b, b, b};
#pragma unroll
          for (int kt = 0; kt < 4; kt++) acc = MFMA(A[kt], Bx[mat][kt], acc);
          h4 o;
#pragma unroll
          for (int rr = 0; rr < 4; rr++) o[rr] = (f16)acc[rr];
          *(h4*)(XU0w + ((size_t)mt * NT0 + mat * 10 + w) * 256 + lane * 4) = o;
        }
        __syncthreads();
      }
      signal(&CNT[(C_X0 + cn) * CSTRIDE]);
    }
  }
}

extern "C" void kernel_launch(void* const* d_in, const int* in_sizes, int n_in,
                              void* d_out, int out_size, void* d_ws, size_t ws_size,
                              hipStream_t stream) {
  const float* w1_0 = (const float*)d_in[0];
  const float* w2_0 = (const float*)d_in[1];
  const float* wa_0 = (const float*)d_in[2];
  const float* wb_0 = (const float*)d_in[3];
  const float* b1_0 = (const float*)d_in[4];
  const float* b2_0 = (const float*)d_in[5];
  const float* ba_0 = (const float*)d_in[6];
  const float* bb_0 = (const float*)d_in[7];
  const int* m0 = (const int*)d_in[8];
  const float* w1_1 = (const float*)d_in[9];
  const float* w2_1 = (const float*)d_in[10];
  const float* wa_1 = (const float*)d_in[11];
  const float* wb_1 = (const float*)d_in[12];
  const float* b1_1 = (const float*)d_in[13];
  const float* b2_1 = (const float*)d_in[14];
  const float* ba_1 = (const float*)d_in[15];
  const float* bb_1 = (const float*)d_in[16];
  const int* m1 = (const int*)d_in[17];
  const float* w1_2 = (const float*)d_in[18];
  const float* w2_2 = (const float*)d_in[19];
  const float* wa_2 = (const float*)d_in[20];
  const float* wb_2 = (const float*)d_in[21];
  const float* c1 = (const float*)d_in[22];
  const float* c2 = (const float*)d_in[23];
  const float* ca = (const float*)d_in[24];
  const float* cb = (const float*)d_in[25];
  const int* m2 = (const int*)d_in[26];
  const float* x = (const float*)d_in[27];
  const float* dt = (const float*)d_in[28];
  float* out = (float*)d_out;

  f16* XU0 = (f16*)d_ws;                 // 2 x XU0C
  f16* NH0 = XU0 + 2 * XU0C;             // 2 x NH0C
  f16* XU1 = NH0 + 2 * NH0C;             // 2 x XU1C
  f16* PK = XU1 + 2 * XU1C;
  int* CNT = (int*)(PK + (size_t)NFRAG * 8);
  const h8* pk = (const h8*)PK;

  // R12 FIX: zero ALL handshake counters before pack (R11 left idx>=256 dirty).
  hipMemsetAsync(CNT, 0, NCNT * sizeof(int), stream);

  pack_kernel<<<(NFRAG + 255) / 256, 256, 0, stream>>>(
      w1_0, w2_0, wa_0, wb_0, m0, w1_1, w2_1, wa_1, wb_1, m1,
      w1_2, w2_2, wa_2, wb_2, m2, dt, PK, CNT);

  R_kernel<<<2 * NBT + NXWG1 + NXWG0, 640, 0, stream>>>(
      pk, b1_0, b2_0, ba_0, bb_0, b1_1, b2_1, ba_1, bb_1,
      c1, c2, ca, cb, dt, x, XU0, NH0, XU1, CNT, out);
}

// Round 8
// 705.991 us; speedup vs baseline: 1.1940x; 1.1940x over previous
//
#include <hip/hip_runtime.h>
#include <cmath>

// CfC-NCP RNN, phase-decomposed + chunk-pipelined.
// R13: R10 chassis (733us proven, 10 launches) + windowed r12 stream to kill
// the 70us tail. Launch c = [ r0(c) | r12 subs 4c-2..4c+1 | x1 subs
// {(c-1,k3),(c,k0..2)} | x0(c+1) ], sub = 16 timesteps.
//  - r12 global sub G (chunk m=G/4, k=G%4) gated on X1SUB[G] (release/acquire,
//    R10-proven machinery; r12/x1 have slack for the fence costs).
//  - x1 sub G gated on R0SUB[G], which r0 signals every 16 steps. To avoid the
//    R12 lesson (agent-release = L2 writeback ~3us on the PACER's path):
//    r0's NH0 stores are sc0/sc1 (agent-coherent write-through) inline-asm
//    stores; x1 reads NH0 with sc0/sc1 loads; r0's signals and x1's spins are
//    then RELAXED counter-only (no fences, no wbl2 on r0).
//  - Tail launch 8 = x1(sub31) + r12(subs 30,31) ~= 32us (was 70).
//  - R12 lesson #2: wall = dispatch_sum + ~110us fixed harness overhead;
//    only dispatch-sum matters. R12's persistent kernel (718) lost to R10's
//    launch sum (634) because of per-chunk fence costs on r0.
// Carried: packed weights, merged -(ts*wa+wb), -2*log2e pre-scale, depth-4 r0
// xu prefetch, depth-2 r12 xu prefetch (clamped per-sub), raw lgkmcnt-only
// barriers, single-rcp exp2 epilogue. R8/R6: r12 stays recurrent-only + bulk x1.

typedef _Float16 f16;
typedef f16 h4 __attribute__((ext_vector_type(4)));
typedef f16 h8 __attribute__((ext_vector_type(8)));
typedef float f4 __attribute__((ext_vector_type(4)));

#define MFMA(a, b, c) __builtin_amdgcn_mfma_f32_16x16x32_f16(a, b, c, 0, 0, 0)
#define RAW_BAR() asm volatile("s_waitcnt lgkmcnt(0)\n\ts_barrier" ::: "memory")

constexpr int IN_DIM = 128, Ni = 149, Nc = 99, Nm = 8;
constexpr int CAT0 = 277, CAT1 = 248, CAT2 = 107;
constexpr int Bsz = 256, Tsz = 512;
constexpr int TC = 64, NCH = 8, NBT = 16;
constexpr int NSUB = NCH * 4;            // 32 global 16-step sub-chunks
constexpr int NT0 = 30, NT1 = 21;        // fragment tile-columns (3 mats x n-tiles)
constexpr int S0 = 168, S2 = 136;        // LDS row strides (halves), bank-conflict pad
constexpr int NXWG1 = 64;                // x1 workgroups (1 timestep each)
constexpr int NXWG0 = 128;               // x0 workgroups
constexpr size_t XU0C = (size_t)TC * NBT * NT0 * 256;  // 7,864,320 halves / buffer
constexpr size_t NH0C = (size_t)TC * NBT * 2560;       // 2,621,440 halves / buffer
constexpr size_t XU1C = (size_t)TC * NBT * NT1 * 256;  // 5,505,024 halves / buffer
constexpr size_t H0S_HALVES = (size_t)NBT * 16 * S0;
constexpr size_t H12S_HALVES = (size_t)NBT * 2 * 16 * S2;
constexpr size_t YOFF = (size_t)Bsz * Tsz * 8;  // h_out offset in d_out
constexpr float L2E = 1.4426950408889634f;      // log2(e), folded into weights

// packed-fragment segment offsets (h8 units); mat2 = merged -(ts*wa+wb)
constexpr int OFF_X0 = 0;          // [mat3][nt10][kt4][lane64]
constexpr int OFF_R0 = 7680;       // [g10][mat3][kt5][lane64]
constexpr int OFF_X1 = 17280;      // [mat3][nt7][kt5][lane64]
constexpr int OFF_R12A = 24000;    // [w7][mat3][kt4][lane64]
constexpr int OFF_R12B = 29376;    // [mat3][kt4][lane64]
constexpr int NFRAG = 30144;

// counters, 64B apart: X0DONE[8] (tgt 128), R0SUB[32] (tgt 16),
// X1SUB[32] (tgt 16), R12SUB[32] (tgt 16)
constexpr int CSTRIDE = 16;
constexpr int C_X0 = 0, C_R0S = 8, C_X1S = 40, C_R12S = 72;
constexpr int NCNT = 104 * CSTRIDE;

__device__ inline float rcpf_(float x) { return __builtin_amdgcn_rcpf(x); }
__device__ __forceinline__ float exp2p_(float x) {
#if __has_builtin(__builtin_amdgcn_exp2f)
  return __builtin_amdgcn_exp2f(x);
#else
  return exp2f(x);
#endif
}
// h = ff1 + (ff2-ff1)*ti with ff=(1-e)/(1+e), ti=1/(1+c).
// a0=-2u1*L2E, a1=-2u2*L2E, a2=-z*L2E (scales pre-folded into weights/biases).
__device__ __forceinline__ float cfc_h(float a0, float a1, float a2) {
  float e0 = exp2p_(a0), e1 = exp2p_(a1), e2 = exp2p_(a2);
  float pa = 1.f + e0, ma = 1.f - e0;
  float pb = 1.f + e1, mb = 1.f - e1;
  float pc = 1.f + e2;
  float num = fmaf(ma * pb, e2, mb * pa);
  return num * rcpf_(pa * pb * pc);
}
__device__ __forceinline__ float tanhp_(float x) {  // tanh(x)
  float e = exp2p_(-2.f * L2E * x);
  return (1.f - e) * rcpf_(1.f + e);
}

// ---- handshake primitives ------------------------------------------------------------
// counter-only gate: no data acquire needed (data is sc1-coherent or cross-launch)
__device__ __forceinline__ void spin_relaxed(int* p, int target) {
  if (threadIdx.x == 0) {
    long it = 0;
    while (__hip_atomic_load(p, __ATOMIC_RELAXED, __HIP_MEMORY_SCOPE_AGENT) <
               target &&
           ++it < (1L << 22))
      __builtin_amdgcn_s_sleep(4);
  }
  __syncthreads();
}
// gate + agent acquire (data published via release; invalidates local L2)
__device__ __forceinline__ void spin_acq(int* p, int target) {
  spin_relaxed(p, target);
  __builtin_amdgcn_fence(__ATOMIC_ACQUIRE, "agent");
}
// __syncthreads drains each wave's vmcnt (all stores complete) before the add.
__device__ __forceinline__ void sig_relaxed(int* p) {
  __syncthreads();
  if (threadIdx.x == 0)
    __hip_atomic_fetch_add(p, 1, __ATOMIC_RELAXED, __HIP_MEMORY_SCOPE_AGENT);
}
__device__ __forceinline__ void sig_rel(int* p) {
  __syncthreads();
  if (threadIdx.x == 0)
    __hip_atomic_fetch_add(p, 1, __ATOMIC_RELEASE, __HIP_MEMORY_SCOPE_AGENT);
}

// ---- agent-coherent (sc0 sc1) data access: write-through stores / cache-bypass loads -
__device__ __forceinline__ void store_short_sc(f16* p, f16 v) {
  unsigned u = (unsigned)__builtin_bit_cast(unsigned short, v);
  asm volatile("global_store_short %0, %1, off sc0 sc1" ::"v"(
                   (unsigned long long)p),
               "v"(u)
               : "memory");
}
__device__ __forceinline__ void load_A5_sc(const f16* base, h8 (&A)[5]) {
  unsigned long long b = (unsigned long long)base;
  asm volatile(
      "global_load_dwordx4 %0, %5, off sc0 sc1\n\t"
      "global_load_dwordx4 %1, %5, off offset:64 sc0 sc1\n\t"
      "global_load_dwordx4 %2, %5, off offset:128 sc0 sc1\n\t"
      "global_load_dwordx4 %3, %5, off offset:192 sc0 sc1\n\t"
      "global_load_dwordx4 %4, %5, off offset:256 sc0 sc1\n\t"
      "s_waitcnt vmcnt(0)"
      : "=&v"(A[0]), "=&v"(A[1]), "=&v"(A[2]), "=&v"(A[3]), "=&v"(A[4])
      : "v"(b)
      : "memory");
}

// ---------------- pack: build all h8 weight fragments + zero counters ----------------
__global__ __launch_bounds__(256) void pack_kernel(
    const float* __restrict__ w1_0, const float* __restrict__ w2_0,
    const float* __restrict__ wa_0, const float* __restrict__ wb_0,
    const int* __restrict__ m0,
    const float* __restrict__ w1_1, const float* __restrict__ w2_1,
    const float* __restrict__ wa_1, const float* __restrict__ wb_1,
    const int* __restrict__ m1,
    const float* __restrict__ w1_2, const float* __restrict__ w2_2,
    const float* __restrict__ wa_2, const float* __restrict__ wb_2,
    const int* __restrict__ m2, const float* __restrict__ dtp,
    f16* __restrict__ PK, int* __restrict__ CNT) {
  if (blockIdx.x == 0)  // grid-stride covers ALL counters (R11 lesson)
    for (int i = threadIdx.x; i < NCNT; i += 256)
      __hip_atomic_store(&CNT[i], 0, __ATOMIC_RELAXED, __HIP_MEMORY_SCOPE_AGENT);
  int idx = blockIdx.x * 256 + threadIdx.x;
  if (idx >= NFRAG) return;
  int lane = idx & 63, col = lane & 15, q = lane >> 4;
  float ts = dtp[0];
  const float* Wa = nullptr;
  const float* Wb = nullptr;
  const int* M = nullptr;
  int ld, n, nmax, k0, kmax;
  int mat;
  if (idx < OFF_R0) {  // x0 input-part
    int p = idx >> 6;
    mat = p / 40; int nt = (p >> 2) % 10, kt = p & 3;
    ld = CAT0; n = nt * 16 + col; nmax = Ni; k0 = kt * 32 + q * 8; kmax = IN_DIM;
    if (mat == 0) { Wa = w1_0; M = m0; }
    else if (mat == 1) { Wa = w2_0; M = m0; }
    else { Wa = wa_0; Wb = wb_0; }
  } else if (idx < OFF_X1) {  // r0 recurrent-part
    int p = (idx - OFF_R0) >> 6;
    int g = p / 15; mat = (p / 5) % 3; int kt = p % 5;
    ld = CAT0; n = g * 16 + col; nmax = Ni; k0 = IN_DIM + kt * 32 + q * 8; kmax = CAT0;
    if (mat == 0) Wa = w1_0;
    else if (mat == 1) Wa = w2_0;
    else { Wa = wa_0; Wb = wb_0; }
  } else if (idx < OFF_R12A) {  // x1 input-part
    int p = (idx - OFF_X1) >> 6;
    mat = p / 35; int nt = (p / 5) % 7, kt = p % 5;
    ld = CAT1; n = nt * 16 + col; nmax = Nc; k0 = kt * 32 + q * 8; kmax = Ni;
    if (mat == 0) { Wa = w1_1; M = m1; }
    else if (mat == 1) { Wa = w2_1; M = m1; }
    else { Wa = wa_1; Wb = wb_1; }
  } else if (idx < OFF_R12B) {  // r12 layer1 recurrent-part
    int p = (idx - OFF_R12A) >> 6;
    int wv = p / 12; mat = (p / 4) % 3; int kt = p & 3;
    ld = CAT1; n = wv * 16 + col; nmax = Nc; k0 = Ni + kt * 32 + q * 8; kmax = CAT1;
    if (mat == 0) Wa = w1_1;
    else if (mat == 1) Wa = w2_1;
    else { Wa = wa_1; Wb = wb_1; }
  } else {  // r12 layer2 (full cat)
    int p = (idx - OFF_R12B) >> 6;
    mat = p / 4; int kt = p & 3;
    ld = CAT2; n = col; nmax = Nm; k0 = kt * 32 + q * 8; kmax = CAT2;
    if (mat == 0) { Wa = w1_2; M = m2; }
    else if (mat == 1) { Wa = w2_2; M = m2; }
    else { Wa = wa_2; Wb = wb_2; }
  }
  h8 r;
#pragma unroll
  for (int j = 0; j < 8; j++) {
    int k = k0 + j;
    float v = 0.f;
    if (n < nmax && k < kmax) {
      if (mat < 2) {
        v = Wa[(size_t)n * ld + k];
        if (M) v *= (float)M[(size_t)n * ld + k];
        v *= -2.f * L2E;                 // ff pre-scale: acc = -2u*log2(e)
      } else {
        v = -L2E * (ts * Wa[(size_t)n * ld + k] + Wb[(size_t)n * ld + k]);
      }
    }
    r[j] = (f16)v;
  }
  ((h8*)PK)[idx] = r;
}

// ------- r0 one step: consume xu (t), reload xu for t+4 (depth-4 pipeline) -----------
// NH0 writes are sc0/sc1 (agent-coherent) so x1 can read them fence-free.
__device__ __forceinline__ void r0_step(
    const f16* br, f16* bw, const f16* __restrict__ XU0, f16* __restrict__ NH0,
    float* __restrict__ out, const h8 (&Bf)[3][5], h4 (&xu)[3],
    int t, int tload, int bt, int g, int lane, int col, int q, int n, bool last) {
  h8 A[5];
#pragma unroll
  for (int kt = 0; kt < 5; kt++)
    A[kt] = *(const h8*)(br + col * S0 + kt * 32 + q * 8);
  f4 acc0 = {(float)xu[0][0], (float)xu[0][1], (float)xu[0][2], (float)xu[0][3]};
  f4 acc1 = {(float)xu[1][0], (float)xu[1][1], (float)xu[1][2], (float)xu[1][3]};
  f4 acc2 = {(float)xu[2][0], (float)xu[2][1], (float)xu[2][2], (float)xu[2][3]};
  size_t mtl = (size_t)tload * NBT + bt;
#pragma unroll
  for (int mat = 0; mat < 3; mat++)
    xu[mat] = *(const h4*)(XU0 + (mtl * NT0 + mat * 10 + g) * 256 + lane * 4);
#pragma unroll
  for (int kt = 0; kt < 5; kt++) {
    acc0 = MFMA(A[kt], Bf[0][kt], acc0);
    acc1 = MFMA(A[kt], Bf[1][kt], acc1);
    acc2 = MFMA(A[kt], Bf[2][kt], acc2);
  }
  int mt = t * NBT + bt;
  f16* nh = NH0 + (size_t)mt * 2560;
#pragma unroll
  for (int r = 0; r < 4; r++) {
    int m = q * 4 + r;
    float h = cfc_h(acc0[r], acc1[r], acc2[r]);
    f16 h16 = (f16)h;
    bw[m * S0 + n] = h16;
    store_short_sc(nh + (size_t)m * 160 + n, h16);  // cols >= Ni stay exact zeros
    if (last && n < Ni) out[YOFF + (size_t)(bt * 16 + m) * 256 + n] = h;
  }
}

// ------- r12 layer1 one step: consume xu(t), reload xu for tload (sub-clamped) -------
__device__ __forceinline__ void r12l1_step(
    const f16* br, f16* bw, const f16* __restrict__ XU1, float* __restrict__ out,
    const h8 (&Bf)[3][4], h4 (&xu)[3],
    int tload, int bt, int w, int lane, int col, int q, int n, bool last) {
  h8 A[4];
#pragma unroll
  for (int kt = 0; kt < 4; kt++)
    A[kt] = *(const h8*)(br + col * S2 + kt * 32 + q * 8);
  f4 acc0 = {(float)xu[0][0], (float)xu[0][1], (float)xu[0][2], (float)xu[0][3]};
  f4 acc1 = {(float)xu[1][0], (float)xu[1][1], (float)xu[1][2], (float)xu[1][3]};
  f4 acc2 = {(float)xu[2][0], (float)xu[2][1], (float)xu[2][2], (float)xu[2][3]};
  size_t mtl = (size_t)tload * NBT + bt;
#pragma unroll
  for (int mat = 0; mat < 3; mat++)
    xu[mat] = *(const h4*)(XU1 + (mtl * NT1 + mat * 7 + w) * 256 + lane * 4);
#pragma unroll
  for (int kt = 0; kt < 4; kt++) {
    acc0 = MFMA(A[kt], Bf[0][kt], acc0);
    acc1 = MFMA(A[kt], Bf[1][kt], acc1);
    acc2 = MFMA(A[kt], Bf[2][kt], acc2);
  }
#pragma unroll
  for (int r = 0; r < 4; r++) {
    int m = q * 4 + r;
    float h = cfc_h(acc0[r], acc1[r], acc2[r]);
    if (n < Nc) {
      bw[m * S2 + n] = (f16)h;
      if (last) out[YOFF + (size_t)(bt * 16 + m) * 256 + Ni + n] = h;
    }
  }
}

// ------- r12 layer2 one step: reads rb (nh1(t)|h2(t-1)), writes h2(t) into wb --------
__device__ __forceinline__ void r12l2_step(
    const f16* rb, f16* wb, float* __restrict__ out, const h8 (&Bf)[3][4],
    float bn0, float bn1, float bn2, int tg, int bt, int col, int q, bool last) {
  h8 A[4];
#pragma unroll
  for (int kt = 0; kt < 4; kt++)
    A[kt] = *(const h8*)(rb + col * S2 + kt * 32 + q * 8);
  f4 acc0 = {bn0, bn0, bn0, bn0};
  f4 acc1 = {bn1, bn1, bn1, bn1};
  f4 acc2 = {bn2, bn2, bn2, bn2};
#pragma unroll
  for (int kt = 0; kt < 4; kt++) {
    acc0 = MFMA(A[kt], Bf[0][kt], acc0);
    acc1 = MFMA(A[kt], Bf[1][kt], acc1);
    acc2 = MFMA(A[kt], Bf[2][kt], acc2);
  }
#pragma unroll
  for (int r = 0; r < 4; r++) {
    int m = q * 4 + r;
    float h = cfc_h(acc0[r], acc1[r], acc2[r]);
    if (col < Nm) {
      out[((size_t)(bt * 16 + m) * Tsz + tg) * 8 + col] = tanhp_(h);
      wb[m * S2 + Nc + col] = (f16)h;
      if (last) out[YOFF + (size_t)(bt * 16 + m) * 256 + Ni + Nc + col] = h;
    }
  }
}

// ---- R: [r0(c) 0-15 | r12 subs 16-31 | x1 subs 32-95 | x0(c+1) 96-223] --------------
__global__ __launch_bounds__(640) void R_kernel(
    const h8* __restrict__ pk,
    const float* __restrict__ b1_0, const float* __restrict__ b2_0,
    const float* __restrict__ ba_0, const float* __restrict__ bb_0,
    const float* __restrict__ b1_1, const float* __restrict__ b2_1,
    const float* __restrict__ ba_1, const float* __restrict__ bb_1,
    const float* __restrict__ c1, const float* __restrict__ c2,
    const float* __restrict__ ca, const float* __restrict__ cb,
    const float* __restrict__ dtp, const float* __restrict__ x,
    f16* __restrict__ XU0, f16* __restrict__ NH0, f16* __restrict__ XU1,
    f16* __restrict__ H0S, f16* __restrict__ H12S,
    int* __restrict__ CNT, float* __restrict__ out, int c) {
  __shared__ __align__(16) char smem[10752];  // union: r0 10752 / r12 8704 / x0 4352
  int tid = threadIdx.x;
  int g = tid >> 6, lane = tid & 63, col = lane & 15, q = lane >> 4;
  int wg = blockIdx.x;
  float ts = dtp[0];

  if (wg < NBT) {  // ================= r0, chunk c =================
    if (c < 0 || c >= NCH) return;
    spin_relaxed(&CNT[(C_X0 + c) * CSTRIDE], NXWG0);       // XU0[c&1] ready (prev launch)
    if (c >= 2)                                            // NH0[c&1] free (counter-only)
      spin_relaxed(&CNT[(C_X1S + 4 * (c - 2) + 3) * CSTRIDE], NBT);
    const f16* XU0r = XU0 + (size_t)(c & 1) * XU0C;
    f16* NH0w = NH0 + (size_t)(c & 1) * NH0C;
    f16(*buf)[16 * S0] = (f16(*)[16 * S0])smem;
    int bt = wg;
    int n = g * 16 + col;                      // output neuron (0..159, valid <149)
    h8 Bf[3][5];                               // recurrent weights, resident
#pragma unroll
    for (int mat = 0; mat < 3; mat++)
#pragma unroll
      for (int kt = 0; kt < 5; kt++)
        Bf[mat][kt] = pk[OFF_R0 + ((g * 3 + mat) * 5 + kt) * 64 + lane];

    for (int idx = tid; idx < 16 * S0; idx += 640) {
      buf[0][idx] = (c == 0) ? (f16)0.f : H0S[(size_t)bt * 16 * S0 + idx];
      buf[1][idx] = (f16)0.f;
    }
    __syncthreads();

    h4 xu0[3], xu1[3], xu2[3], xu3[3];         // depth-4 prefetch (2-step lead)
#pragma unroll
    for (int mat = 0; mat < 3; mat++) {
      xu0[mat] = *(const h4*)(XU0r + ((size_t)(0 * NBT + bt) * NT0 + mat * 10 + g) * 256 + lane * 4);
      xu1[mat] = *(const h4*)(XU0r + ((size_t)(1 * NBT + bt) * NT0 + mat * 10 + g) * 256 + lane * 4);
      xu2[mat] = *(const h4*)(XU0r + ((size_t)(2 * NBT + bt) * NT0 + mat * 10 + g) * 256 + lane * 4);
      xu3[mat] = *(const h4*)(XU0r + ((size_t)(3 * NBT + bt) * NT0 + mat * 10 + g) * 256 + lane * 4);
    }

    for (int t = 0; t < TC; t += 4) {
      r0_step(buf[0], buf[1], XU0r, NH0w, out, Bf, xu0, t, (t + 4 < TC) ? t + 4 : t,
              bt, g, lane, col, q, n, false);
      RAW_BAR();
      r0_step(buf[1], buf[0], XU0r, NH0w, out, Bf, xu1, t + 1,
              (t + 5 < TC) ? t + 5 : t + 1, bt, g, lane, col, q, n, false);
      RAW_BAR();
      r0_step(buf[0], buf[1], XU0r, NH0w, out, Bf, xu2, t + 2,
              (t + 6 < TC) ? t + 6 : t + 2, bt, g, lane, col, q, n, false);
      RAW_BAR();
      bool lastD = (c == NCH - 1) && (t + 3 == TC - 1);
      r0_step(buf[1], buf[0], XU0r, NH0w, out, Bf, xu3, t + 3,
              (t + 7 < TC) ? t + 7 : t + 3, bt, g, lane, col, q, n, lastD);
      RAW_BAR();
      if ((t & 12) == 12)  // end of sub (t>>4): publish NH0 sub (sc1 stores drained
                           // by sig's syncthreads; relaxed add - no wbl2 on pacer)
        sig_relaxed(&CNT[(C_R0S + 4 * c + (t >> 4)) * CSTRIDE]);
    }
    for (int idx = tid; idx < 16 * S0; idx += 640)
      H0S[(size_t)bt * 16 * S0 + idx] = buf[0][idx];

  } else if (wg < 2 * NBT) {  // ========= r12: global subs [4c-2, 4c+1] =========
    int Glo = 4 * c - 2; if (Glo < 0) Glo = 0;
    int Ghi = 4 * c + 1; if (Ghi > NSUB - 1) Ghi = NSUB - 1;
    if (Glo > Ghi || c < 0) return;
    f16(*buf)[16 * S2] = (f16(*)[16 * S2])smem;
    int bt = wg - NBT;
    int w = g;                                 // wave id 0..9 (8,9 barrier-only)
    int n = w * 16 + col;
    h8 Bf[3][4];
    float bn0 = 0.f, bn1 = 0.f, bn2 = 0.f;
    if (w < 7) {
#pragma unroll
      for (int mat = 0; mat < 3; mat++)
#pragma unroll
        for (int kt = 0; kt < 4; kt++)
          Bf[mat][kt] = pk[OFF_R12A + ((w * 3 + mat) * 4 + kt) * 64 + lane];
    } else if (w == 7) {
#pragma unroll
      for (int mat = 0; mat < 3; mat++)
#pragma unroll
        for (int kt = 0; kt < 4; kt++)
          Bf[mat][kt] = pk[OFF_R12B + (mat * 4 + kt) * 64 + lane];
      bn0 = (col < Nm) ? -2.f * L2E * c1[col] : 0.f;
      bn1 = (col < Nm) ? -2.f * L2E * c2[col] : 0.f;
      bn2 = (col < Nm) ? -L2E * (ts * ca[col] + cb[col]) : 0.f;
    }
    for (int idx = tid; idx < 2 * 16 * S2; idx += 640)
      ((f16*)buf)[idx] = (Glo == 0) ? (f16)0.f : H12S[(size_t)bt * 2 * 16 * S2 + idx];
    __syncthreads();

    for (int G = Glo; G <= Ghi; ++G) {
      int m = G >> 2, t0 = (G & 3) * 16;
      spin_acq(&CNT[(C_X1S + G) * CSTRIDE], NBT);          // XU1 sub ready (acquire)
      const f16* XU1r = XU1 + (size_t)(m & 1) * XU1C;
      h4 xuA[3], xuB[3];                       // depth-2 prefetch, per-sub
      if (w < 7) {
#pragma unroll
        for (int mat = 0; mat < 3; mat++) {
          xuA[mat] = *(const h4*)(XU1r + ((size_t)(t0 * NBT + bt) * NT1 + mat * 7 + w) * 256 + lane * 4);
          xuB[mat] = *(const h4*)(XU1r +
                                  ((size_t)((t0 + 1) * NBT + bt) * NT1 + mat * 7 + w) * 256 + lane * 4);
        }
      }
      for (int t = t0; t < t0 + 16; t += 2) {
        if (w < 7) {
          int tlA = (t + 2 < t0 + 16) ? t + 2 : t;   // clamp reloads within sub
          r12l1_step(buf[0], buf[1], XU1r, out, Bf, xuA, tlA, bt, w, lane, col, q, n,
                     false);
        }
        RAW_BAR();
        if (w == 7)
          r12l2_step(buf[1], buf[0], out, Bf, bn0, bn1, bn2, m * TC + t, bt, col, q,
                     false);
        if (w < 7) {
          int tlB = (t + 3 < t0 + 16) ? t + 3 : t + 1;
          bool lastB = (m == NCH - 1) && (t + 1 == TC - 1);
          r12l1_step(buf[1], buf[0], XU1r, out, Bf, xuB, tlB, bt, w, lane, col, q, n,
                     lastB);
        }
        RAW_BAR();
        if (w == 7)
          r12l2_step(buf[0], buf[1], out, Bf, bn0, bn1, bn2, m * TC + t + 1, bt, col,
                     q, (m == NCH - 1) && (t + 1 == TC - 1));
      }
      sig_relaxed(&CNT[(C_R12S + G) * CSTRIDE]);  // XU1 sub consumed (counter-only)
    }
    for (int idx = tid; idx < 2 * 16 * S2; idx += 640)
      H12S[(size_t)bt * 2 * 16 * S2 + idx] = ((f16*)buf)[idx];

  } else if (wg < 2 * NBT + NXWG1) {  // ===== x1: one sub task per WG ==========
    int bx = wg - 2 * NBT;                     // timestep t = bx; sub k = bx>>4
    int k = bx >> 4;
    int m = (k == 3) ? c - 1 : c;              // chunk this WG serves this launch
    if (m < 0 || m >= NCH) return;
    int G = 4 * m + k;
    int w = g;                                 // waves 0-6 active, 7-9 spin/sync only
    int n = w * 16 + col;
    h8 Bf[3][5];
    float bias[3] = {0.f, 0.f, 0.f};
    if (w < 7) {
#pragma unroll
      for (int mat = 0; mat < 3; mat++)
#pragma unroll
        for (int kt = 0; kt < 5; kt++)
          Bf[mat][kt] = pk[OFF_X1 + (mat * 35 + w * 5 + kt) * 64 + lane];
      bias[0] = (n < Nc) ? -2.f * L2E * b1_1[n] : 0.f;
      bias[1] = (n < Nc) ? -2.f * L2E * b2_1[n] : 0.f;
      bias[2] = (n < Nc) ? -L2E * (ts * ba_1[n] + bb_1[n]) : 0.f;
    }
    spin_relaxed(&CNT[(C_R0S + G) * CSTRIDE], NBT);        // NH0 sub ready (sc1 data)
    if (m >= 2)                                            // XU1[m&1] free
      spin_relaxed(&CNT[(C_R12S + 4 * (m - 2) + 3) * CSTRIDE], NBT);
    const f16* NH0r = NH0 + (size_t)(m & 1) * NH0C;
    f16* XU1w = XU1 + (size_t)(m & 1) * XU1C;
    if (w < 7) {
      for (int i = 0; i < 16; i++) {           // 16 bt tiles of timestep t=bx
        int mt = bx * 16 + i;
        const f16* base = NH0r + (size_t)mt * 2560 + col * 160 + q * 8;
        h8 A[5];
        load_A5_sc(base, A);                   // agent-coherent reads, fence-free
#pragma unroll
        for (int mat = 0; mat < 3; mat++) {
          float b = bias[mat];
          f4 acc = {b, b, b, b};
#pragma unroll
          for (int kt = 0; kt < 5; kt++) acc = MFMA(A[kt], Bf[mat][kt], acc);
          h4 o;
#pragma unroll
          for (int rr = 0; rr < 4; rr++) o[rr] = (f16)acc[rr];
          *(h4*)(XU1w + ((size_t)mt * NT1 + mat * 7 + w) * 256 + lane * 4) = o;
        }
      }
    }
    sig_rel(&CNT[(C_X1S + G) * CSTRIDE]);      // RELEASE publishes XU1 (x1 has slack)

  } else {  // ================= x0 for chunk c+1 (no recurrence dep) =================
    int cn = c + 1;
    if (cn >= NCH) return;
    if (cn >= 2)                               // XU0[cn&1] free (counter-only)
      spin_relaxed(&CNT[(C_R0S + 4 * (cn - 2) + 3) * CSTRIDE], NBT);
    f16* XU0w = XU0 + (size_t)(cn & 1) * XU0C;
    f16* stg = (f16*)smem;                     // 16 x 136
    int bx = wg - 2 * NBT - NXWG1;             // 0..NXWG0-1
    int w = g;                                 // wave -> output tile g=w, all 3 mats
    int n = w * 16 + col;
    h8 Bx[3][4];
    float bias[3];
#pragma unroll
    for (int mat = 0; mat < 3; mat++)
#pragma unroll
      for (int kt = 0; kt < 4; kt++)
        Bx[mat][kt] = pk[OFF_X0 + ((mat * 10 + w) * 4 + kt) * 64 + lane];
    bias[0] = (n < Ni) ? -2.f * L2E * b1_0[n] : 0.f;
    bias[1] = (n < Ni) ? -2.f * L2E * b2_0[n] : 0.f;
    bias[2] = (n < Ni) ? -L2E * (ts * ba_0[n] + bb_0[n]) : 0.f;
    for (int i = 0; i < (TC * NBT) / NXWG0; i++) {   // 8 mt tiles per WG
      int mt = bx * ((TC * NBT) / NXWG0) + i;
      int tl = mt >> 4, bt = mt & 15;
      int tg = cn * TC + tl;
      if (tid < 256) {
        int sr = tid >> 4, sc = (tid & 15) * 8;
        const float* xp = x + ((size_t)(bt * 16 + sr) * Tsz + tg) * IN_DIM + sc;
        h8 hv;
#pragma unroll
        for (int j = 0; j < 8; j++) hv[j] = (f16)xp[j];
        *(h8*)(stg + sr * 136 + sc) = hv;
      }
      __syncthreads();
      h8 A[4];
#pragma unroll
      for (int kt = 0; kt < 4; kt++)
        A[kt] = *(const h8*)(stg + col * 136 + kt * 32 + q * 8);
#pragma unroll
      for (int mat = 0; mat < 3; mat++) {
        float b = bias[mat];
        f4 acc = {b, b, b, b};
#pragma unroll
        for (int kt = 0; kt < 4; kt++) acc = MFMA(A[kt], Bx[mat][kt], acc);
        h4 o;
#pragma unroll
        for (int rr = 0; rr < 4; rr++) o[rr] = (f16)acc[rr];
        *(h4*)(XU0w + ((size_t)mt * NT0 + mat * 10 + w) * 256 + lane * 4) = o;
      }
      __syncthreads();
    }
    sig_relaxed(&CNT[(C_X0 + cn) * CSTRIDE]);  // consumed next launch (boundary-coherent)
  }
}

extern "C" void kernel_launch(void* const* d_in, const int* in_sizes, int n_in,
                              void* d_out, int out_size, void* d_ws, size_t ws_size,
                              hipStream_t stream) {
  const float* w1_0 = (const float*)d_in[0];
  const float* w2_0 = (const float*)d_in[1];
  const float* wa_0 = (const float*)d_in[2];
  const float* wb_0 = (const float*)d_in[3];
  const float* b1_0 = (const float*)d_in[4];
  const float* b2_0 = (const float*)d_in[5];
  const float* ba_0 = (const float*)d_in[6];
  const float* bb_0 = (const float*)d_in[7];
  const int* m0 = (const int*)d_in[8];
  const float* w1_1 = (const float*)d_in[9];
  const float* w2_1 = (const float*)d_in[10];
  const float* wa_1 = (const float*)d_in[11];
  const float* wb_1 = (const float*)d_in[12];
  const float* b1_1 = (const float*)d_in[13];
  const float* b2_1 = (const float*)d_in[14];
  const float* ba_1 = (const float*)d_in[15];
  const float* bb_1 = (const float*)d_in[16];
  const int* m1 = (const int*)d_in[17];
  const float* w1_2 = (const float*)d_in[18];
  const float* w2_2 = (const float*)d_in[19];
  const float* wa_2 = (const float*)d_in[20];
  const float* wb_2 = (const float*)d_in[21];
  const float* c1 = (const float*)d_in[22];
  const float* c2 = (const float*)d_in[23];
  const float* ca = (const float*)d_in[24];
  const float* cb = (const float*)d_in[25];
  const int* m2 = (const int*)d_in[26];
  const float* x = (const float*)d_in[27];
  const float* dt = (const float*)d_in[28];
  float* out = (float*)d_out;

  f16* XU0 = (f16*)d_ws;                 // 2 x XU0C
  f16* NH0 = XU0 + 2 * XU0C;             // 2 x NH0C
  f16* XU1 = NH0 + 2 * NH0C;             // 2 x XU1C
  f16* H0S = XU1 + 2 * XU1C;
  f16* H12S = H0S + H0S_HALVES;
  f16* PK = H12S + H12S_HALVES;
  int* CNT = (int*)(PK + (size_t)NFRAG * 8);
  const h8* pk = (const h8*)PK;

  hipMemsetAsync(CNT, 0, NCNT * sizeof(int), stream);

  pack_kernel<<<(NFRAG + 255) / 256, 256, 0, stream>>>(
      w1_0, w2_0, wa_0, wb_0, m0, w1_1, w2_1, wa_1, wb_1, m1,
      w1_2, w2_2, wa_2, wb_2, m2, dt, PK, CNT);

  for (int c = -1; c <= NCH; c++)
    R_kernel<<<2 * NBT + NXWG1 + NXWG0, 640, 0, stream>>>(
        pk, b1_0, b2_0, ba_0, bb_0, b1_1, b2_1, ba_1, bb_1,
        c1, c2, ca, cb, dt, x, XU0, NH0, XU1, H0S, H12S, CNT, out, c);
}